// Round 1
// baseline (1377.238 us; speedup 1.0000x reference)
//
#include <hip/hip_runtime.h>

#define N_NODES 50000
#define N_EDGES 800000
#define IN_DIM 128
#define HID 96
#define ATTN_HID 32
#define OUT_DIM 16
#define N_SPOTS 5000
#define GN_EPS 1e-5f

// ---------------- persistent device scratch (re-initialized every call) ----
__device__ float    g_bufA[N_NODES * HID];
__device__ float    g_bufB[N_NODES * HID];
__device__ float    g_bufC[N_NODES * HID];
__device__ float    g_spot[N_SPOTS * HID];
__device__ float    g_dinv[N_NODES];     // deg -> rsqrt(deg)
__device__ float    g_scores[N_NODES];   // scores -> exp(scores - max)
__device__ unsigned g_smax[N_SPOTS];     // monotone-uint encoded segment max
__device__ float    g_denom[N_SPOTS];
__device__ float    g_S[4 * 2 * HID];    // 4 GN stages x (colsum, colsumsq)
__device__ float    g_ab[4 * 2 * HID];   // 4 GN stages x (alpha, beta)

__device__ __forceinline__ float* pick(int id) {
  switch (id) {
    case 0:  return g_bufA;
    case 1:  return g_bufB;
    case 2:  return g_bufC;
    default: return g_spot;
  }
}

// ---------------- init: zero/seed all accumulators ------------------------
__global__ __launch_bounds__(256) void k_init() {
  int i = blockIdx.x * 256 + threadIdx.x;
  if (i < N_SPOTS * HID) g_spot[i] = 0.f;
  if (i < N_NODES) g_dinv[i] = 1.f;   // self-loop contributes 1 to degree
  if (i < N_SPOTS) { g_smax[i] = 0u; g_denom[i] = 0.f; }
  if (i < 4 * 2 * HID) g_S[i] = 0.f;
}

__global__ __launch_bounds__(256) void k_deg(const int* __restrict__ dst) {
  int e = blockIdx.x * 256 + threadIdx.x;
  if (e < N_EDGES) atomicAdd(&g_dinv[dst[e]], 1.f);
}

__global__ __launch_bounds__(256) void k_rsqrt() {
  int i = blockIdx.x * 256 + threadIdx.x;
  if (i < N_NODES) g_dinv[i] = rsqrtf(g_dinv[i]);
}

// ---------------- GEMM: out[nrows x 96] = act(A) @ W (+bias) --------------
// A is either an external pointer (Aext) or an internal buffer (a_id).
// AFF: apply per-column GN affine + ReLU to the input while staging to LDS.
template <int K, bool AFF>
__global__ __launch_bounds__(256) void k_gemm96(const float* __restrict__ Aext,
                                                int a_id, int out_id,
                                                const float* __restrict__ W,
                                                const float* __restrict__ bias,
                                                int stage, int nrows) {
  __shared__ float Ws[K * HID];
  __shared__ float xs[64 * (K + 4)];
  const float* A = Aext ? Aext : pick(a_id);
  float* out = pick(out_id);
  const float* ab = g_ab + stage * 2 * HID;  // alpha[0..95], beta[96..191]
  int tid = threadIdx.x;
  for (int f = tid; f < K * HID; f += 256) Ws[f] = W[f];
  int r0 = blockIdx.x * 64;
  for (int f = tid; f < 64 * K; f += 256) {
    int r = f / K, c = f - r * K;
    int row = r0 + r;
    float v = (row < nrows) ? A[row * K + c] : 0.f;
    if (AFF) v = fmaxf(v * ab[c] + ab[HID + c], 0.f);  // AFF only used with K==96
    xs[r * (K + 4) + c] = v;
  }
  __syncthreads();
  int r = tid >> 2;
  int c0 = (tid & 3) * 24;
  float acc[24];
#pragma unroll
  for (int c = 0; c < 24; ++c) acc[c] = 0.f;
#pragma unroll 4
  for (int k = 0; k < K; ++k) {
    float xv = xs[r * (K + 4) + k];
#pragma unroll
    for (int c = 0; c < 24; ++c) acc[c] += xv * Ws[k * HID + c0 + c];
  }
  int row = r0 + r;
  if (row < nrows) {
#pragma unroll
    for (int c = 0; c < 24; ++c) {
      float bv = bias ? bias[c0 + c] : 0.f;
      out[row * HID + c0 + c] = acc[c] + bv;
    }
  }
}

// ---------------- GCN aggregation ------------------------------------------
// agg[i] = dinv[i]^2 * t[i] + b   (self loop + bias), then edge scatter adds.
__global__ __launch_bounds__(256) void k_agginit(int t_id, const float* __restrict__ b,
                                                 int agg_id) {
  const float* t = pick(t_id);
  float* agg = pick(agg_id);
  int i = blockIdx.x * 256 + threadIdx.x;
  if (i < N_NODES * HID) {
    int row = i / HID, c = i - row * HID;
    float di = g_dinv[row];
    agg[i] = di * di * t[i] + b[c];
  }
}

// one 32-lane group per edge; 3 dims/lane
__global__ __launch_bounds__(256) void k_scatter(const int* __restrict__ src,
                                                 const int* __restrict__ dst,
                                                 int t_id, int agg_id) {
  const float* t = pick(t_id);
  float* agg = pick(agg_id);
  int g = (blockIdx.x * 256 + threadIdx.x) >> 5;
  int lane = threadIdx.x & 31;
  if (g >= N_EDGES) return;
  int s = src[g], d = dst[g];
  float norm = g_dinv[s] * g_dinv[d];
#pragma unroll
  for (int it = 0; it < 3; ++it) {
    int j = lane + it * 32;
    atomicAdd(&agg[d * HID + j], t[s * HID + j] * norm);
  }
}

// ---------------- GraphNorm stats ------------------------------------------
__global__ __launch_bounds__(256) void k_colstats(int x_id, int stage, int nrows) {
  const float* x = pick(x_id);
  float* S = g_S + stage * 2 * HID;
  int t = threadIdx.x;
  if (t >= 192) return;
  int c = (t < 96) ? t : t - 96;
  int phase = t / 96;
  int r0 = blockIdx.x * 512;
  int rend = min(r0 + 512, nrows);
  float s1 = 0.f, s2 = 0.f;
  for (int r = r0 + phase; r < rend; r += 2) {
    float v = x[r * HID + c];
    s1 += v;
    s2 += v * v;
  }
  atomicAdd(&S[c], s1);
  atomicAdd(&S[HID + c], s2);
}

// y = w*(x - a*mean)*rsqrt(var+eps) + b  ==  x*alpha + beta
// var = S2/n + mean^2*(a^2 - 2a)
__global__ void k_gnparams(int stage, const float* __restrict__ w,
                           const float* __restrict__ b, const float* __restrict__ a,
                           float invn) {
  int c = threadIdx.x;
  if (c < HID) {
    const float* S = g_S + stage * 2 * HID;
    float* ab = g_ab + stage * 2 * HID;
    float mean = S[c] * invn;
    float var = S[HID + c] * invn + mean * mean * (a[c] * a[c] - 2.f * a[c]);
    float r = rsqrtf(var + GN_EPS);
    float alpha = w[c] * r;
    ab[c] = alpha;
    ab[HID + c] = b[c] - alpha * a[c] * mean;
  }
}

// y = relu(x*alpha + beta) materialized (for h2: used twice downstream)
__global__ __launch_bounds__(256) void k_affrelu(int x_id, int stage, int y_id) {
  const float* x = pick(x_id);
  float* y = pick(y_id);
  const float* ab = g_ab + stage * 2 * HID;
  int i = blockIdx.x * 256 + threadIdx.x;
  if (i < N_NODES * HID) {
    int c = i % HID;
    y[i] = fmaxf(x[i] * ab[c] + ab[HID + c], 0.f);
  }
}

// ---------------- attention scores + segment max ---------------------------
__global__ __launch_bounds__(256) void k_scores(int h_id,
                                                const float* __restrict__ W1,
                                                const float* __restrict__ b1,
                                                const float* __restrict__ W2,
                                                const float* __restrict__ b2,
                                                const int* __restrict__ c2s) {
  __shared__ float W1s[HID * ATTN_HID];
  __shared__ float b1s[ATTN_HID], W2s[ATTN_HID];
  const float* h = pick(h_id);
  int tid = threadIdx.x;
  for (int f = tid; f < HID * ATTN_HID; f += 256) W1s[f] = W1[f];
  if (tid < ATTN_HID) { b1s[tid] = b1[tid]; W2s[tid] = W2[tid]; }
  __syncthreads();
  int i = blockIdx.x * 256 + tid;
  if (i >= N_NODES) return;
  float acc[ATTN_HID];
#pragma unroll
  for (int k = 0; k < ATTN_HID; ++k) acc[k] = 0.f;
  for (int j = 0; j < HID; ++j) {
    float hv = h[i * HID + j];
#pragma unroll
    for (int k = 0; k < ATTN_HID; ++k) acc[k] += hv * W1s[j * ATTN_HID + k];
  }
  float s = b2[0];
#pragma unroll
  for (int k = 0; k < ATTN_HID; ++k) s += fmaxf(acc[k] + b1s[k], 0.f) * W2s[k];
  g_scores[i] = s;
  unsigned bits = __float_as_uint(s);
  unsigned u = (bits & 0x80000000u) ? ~bits : (bits | 0x80000000u);
  atomicMax(&g_smax[c2s[i]], u);
}

__global__ __launch_bounds__(256) void k_denom(const int* __restrict__ c2s) {
  int i = blockIdx.x * 256 + threadIdx.x;
  if (i < N_NODES) {
    int sp = c2s[i];
    unsigned u = g_smax[sp];
    unsigned bits = (u & 0x80000000u) ? (u & 0x7FFFFFFFu) : ~u;
    float m = __uint_as_float(bits);
    float e = expf(g_scores[i] - m);
    g_scores[i] = e;  // stash exp for the weighted scatter
    atomicAdd(&g_denom[sp], e);
  }
}

// one 32-lane group per node: spot[seg] += h2[i] * attn[i]
__global__ __launch_bounds__(256) void k_spotagg(const int* __restrict__ c2s, int h_id) {
  const float* h = pick(h_id);
  int g = (blockIdx.x * 256 + threadIdx.x) >> 5;
  int lane = threadIdx.x & 31;
  if (g >= N_NODES) return;
  int sp = c2s[g];
  float a = g_scores[g] / g_denom[sp];
#pragma unroll
  for (int it = 0; it < 3; ++it) {
    int j = lane + it * 32;
    atomicAdd(&g_spot[sp * HID + j], h[g * HID + j] * a);
  }
}

// ---------------- final: out = relu(gn(t3)) @ mlp_W2 + b2 ------------------
__global__ __launch_bounds__(256) void k_final(int t3_id, int stage,
                                               const float* __restrict__ W2,
                                               const float* __restrict__ b2,
                                               float* __restrict__ out) {
  __shared__ float W2s[HID * OUT_DIM];
  const float* t3 = pick(t3_id);
  const float* ab = g_ab + stage * 2 * HID;
  int tid = threadIdx.x;
  for (int f = tid; f < HID * OUT_DIM; f += 256) W2s[f] = W2[f];
  __syncthreads();
  int r = blockIdx.x * 16 + (tid >> 4);
  int c = tid & 15;
  if (r >= N_SPOTS) return;
  float acc = b2[c];
  for (int j = 0; j < HID; ++j) {
    float z = fmaxf(t3[r * HID + j] * ab[j] + ab[HID + j], 0.f);
    acc += z * W2s[j * OUT_DIM + c];
  }
  out[r * OUT_DIM + c] = acc;
}

// ---------------------------------------------------------------------------
extern "C" void kernel_launch(void* const* d_in, const int* in_sizes, int n_in,
                              void* d_out, int out_size, void* d_ws, size_t ws_size,
                              hipStream_t stream) {
  const float* x       = (const float*)d_in[0];
  const int*   ei      = (const int*)d_in[1];
  const int*   src     = ei;
  const int*   dst     = ei + N_EDGES;
  const int*   c2s     = (const int*)d_in[2];
  // d_in[3] = num_spots (constant, unused)
  const float* proj_W  = (const float*)d_in[4];
  const float* proj_b  = (const float*)d_in[5];
  const float* gn0_w   = (const float*)d_in[6];
  const float* gn0_b   = (const float*)d_in[7];
  const float* gn0_a   = (const float*)d_in[8];
  const float* gcn1_W  = (const float*)d_in[9];
  const float* gcn1_b  = (const float*)d_in[10];
  const float* gn1_w   = (const float*)d_in[11];
  const float* gn1_b   = (const float*)d_in[12];
  const float* gn1_a   = (const float*)d_in[13];
  const float* gcn2_W  = (const float*)d_in[14];
  const float* gcn2_b  = (const float*)d_in[15];
  const float* gn2_w   = (const float*)d_in[16];
  const float* gn2_b   = (const float*)d_in[17];
  const float* gn2_a   = (const float*)d_in[18];
  const float* attn_W1 = (const float*)d_in[19];
  const float* attn_b1 = (const float*)d_in[20];
  const float* attn_W2 = (const float*)d_in[21];
  const float* attn_b2 = (const float*)d_in[22];
  const float* mlp_W1  = (const float*)d_in[23];
  const float* mlp_b1  = (const float*)d_in[24];
  const float* mlp_gn_w = (const float*)d_in[25];
  const float* mlp_gn_b = (const float*)d_in[26];
  const float* mlp_gn_a = (const float*)d_in[27];
  const float* mlp_W2  = (const float*)d_in[28];
  const float* mlp_b2  = (const float*)d_in[29];
  float* out = (float*)d_out;

  const float invN = 1.f / (float)N_NODES;
  const float invS = 1.f / (float)N_SPOTS;
  const int GB_N   = (N_NODES + 63) / 64;        // gemm blocks over nodes
  const int GB_S   = (N_SPOTS + 63) / 64;        // gemm blocks over spots
  const int CS_N   = (N_NODES + 511) / 512;      // colstats blocks (nodes)
  const int CS_S   = (N_SPOTS + 511) / 512;      // colstats blocks (spots)
  const int EW_NH  = (N_NODES * HID + 255) / 256;

  // init accumulators (spot, deg, smax, denom, colsums)
  k_init<<<(N_SPOTS * HID + 255) / 256, 256, 0, stream>>>();
  // degrees -> dinv
  k_deg<<<(N_EDGES + 255) / 256, 256, 0, stream>>>(dst);
  k_rsqrt<<<(N_NODES + 255) / 256, 256, 0, stream>>>();

  // stage 0: t0 = x @ proj_W + proj_b -> bufA;  GN0 stats
  k_gemm96<IN_DIM, false><<<GB_N, 256, 0, stream>>>(x, -1, 0, proj_W, proj_b, 0, N_NODES);
  k_colstats<<<CS_N, 256, 0, stream>>>(0, 0, N_NODES);
  k_gnparams<<<1, 128, 0, stream>>>(0, gn0_w, gn0_b, gn0_a, invN);

  // GCN layer 1: t1 = relu(gn0(t0)) @ gcn1_W -> bufB; aggregate -> bufA
  k_gemm96<HID, true><<<GB_N, 256, 0, stream>>>(nullptr, 0, 1, gcn1_W, nullptr, 0, N_NODES);
  k_agginit<<<EW_NH, 256, 0, stream>>>(1, gcn1_b, 0);
  k_scatter<<<(N_EDGES * 32) / 256, 256, 0, stream>>>(src, dst, 1, 0);
  k_colstats<<<CS_N, 256, 0, stream>>>(0, 1, N_NODES);
  k_gnparams<<<1, 128, 0, stream>>>(1, gn1_w, gn1_b, gn1_a, invN);

  // GCN layer 2: t2 = relu(gn1(agg1)) @ gcn2_W -> bufC; aggregate -> bufB
  k_gemm96<HID, true><<<GB_N, 256, 0, stream>>>(nullptr, 0, 2, gcn2_W, nullptr, 1, N_NODES);
  k_agginit<<<EW_NH, 256, 0, stream>>>(2, gcn2_b, 1);
  k_scatter<<<(N_EDGES * 32) / 256, 256, 0, stream>>>(src, dst, 2, 1);
  k_colstats<<<CS_N, 256, 0, stream>>>(1, 2, N_NODES);
  k_gnparams<<<1, 128, 0, stream>>>(2, gn2_w, gn2_b, gn2_a, invN);

  // h2 = relu(gn2(agg2)) -> bufA (used by scores and spot aggregation)
  k_affrelu<<<EW_NH, 256, 0, stream>>>(1, 2, 0);

  // attention + segment softmax + spot aggregation
  k_scores<<<(N_NODES + 255) / 256, 256, 0, stream>>>(0, attn_W1, attn_b1, attn_W2, attn_b2, c2s);
  k_denom<<<(N_NODES + 255) / 256, 256, 0, stream>>>(c2s);
  k_spotagg<<<(N_NODES * 32) / 256, 256, 0, stream>>>(c2s, 0);

  // MLP head: t3 = spot @ mlp_W1 + mlp_b1 -> bufC; GN; out = relu(gn(t3)) @ mlp_W2 + b2
  k_gemm96<HID, false><<<GB_S, 256, 0, stream>>>(nullptr, 3, 2, mlp_W1, mlp_b1, 0, N_SPOTS);
  k_colstats<<<CS_S, 256, 0, stream>>>(2, 3, N_SPOTS);
  k_gnparams<<<1, 128, 0, stream>>>(3, mlp_gn_w, mlp_gn_b, mlp_gn_a, invS);
  k_final<<<(N_SPOTS + 15) / 16, 256, 0, stream>>>(2, 3, mlp_W2, mlp_b2, out);
}

// Round 2
// 885.120 us; speedup vs baseline: 1.5560x; 1.5560x over previous
//
#include <hip/hip_runtime.h>

#define N_NODES 50000
#define N_EDGES 800000
#define IN_DIM 128
#define HID 96
#define ATTN_HID 32
#define OUT_DIM 16
#define N_SPOTS 5000
#define GN_EPS 1e-5f

// ---------------- persistent device scratch (re-initialized every call) ----
__device__ float    g_bufA[N_NODES * HID];
__device__ float    g_bufB[N_NODES * HID];
__device__ float    g_bufC[N_NODES * HID];
__device__ float    g_spot[N_SPOTS * HID];
__device__ float    g_dinv[N_NODES];      // rsqrt(deg+1)
__device__ float    g_scores[N_NODES];
__device__ int      g_deg[N_NODES];       // in-degree histogram (edges)
__device__ int      g_degs[N_SPOTS];      // spot histogram (nodes)
__device__ int      g_rp[N_NODES + 1];    // CSR row ptr (by dst)
__device__ int      g_cur[N_NODES];       // fill cursors
__device__ int      g_rps[N_SPOTS + 1];   // spot CSR row ptr
__device__ int      g_curs[N_SPOTS];
__device__ int      g_csrc[N_EDGES];      // CSR src indices
__device__ int      g_cnode[N_NODES];     // spot CSR node indices
__device__ float    g_S[4 * 2 * HID];     // 4 GN stages x (colsum, colsumsq)
__device__ float    g_ab[4 * 2 * HID];    // 4 GN stages x (alpha, beta)

__device__ __forceinline__ float* pick(int id) {
  switch (id) {
    case 0:  return g_bufA;
    case 1:  return g_bufB;
    case 2:  return g_bufC;
    default: return g_spot;
  }
}

// ---------------- init: zero histograms + GN sums --------------------------
__global__ __launch_bounds__(256) void k_init() {
  int i = blockIdx.x * 256 + threadIdx.x;
  if (i < N_NODES) g_deg[i] = 0;
  if (i < N_SPOTS) g_degs[i] = 0;
  if (i < 4 * 2 * HID) g_S[i] = 0.f;
}

// histograms: edge->dst degree, node->spot counts
__global__ __launch_bounds__(256) void k_hist(const int* __restrict__ dst,
                                              const int* __restrict__ c2s) {
  int i = blockIdx.x * 256 + threadIdx.x;
  if (i < N_EDGES) atomicAdd(&g_deg[dst[i]], 1);
  if (i < N_NODES) atomicAdd(&g_degs[c2s[i]], 1);
}

// block 0: scan node degrees -> g_rp/g_cur ; block 1: spots -> g_rps/g_curs
__global__ __launch_bounds__(256) void k_scan() {
  const int  n   = (blockIdx.x == 0) ? N_NODES : N_SPOTS;
  int*       deg = (blockIdx.x == 0) ? g_deg  : g_degs;
  int*       rp  = (blockIdx.x == 0) ? g_rp   : g_rps;
  int*       cur = (blockIdx.x == 0) ? g_cur  : g_curs;
  __shared__ int tmp[256];
  int t = threadIdx.x;
  int chunk = (n + 255) / 256;
  int lo = t * chunk, hi = min(lo + chunk, n);
  int s = 0;
  for (int i = lo; i < hi; ++i) s += deg[i];
  tmp[t] = s;
  __syncthreads();
  // inclusive Hillis-Steele scan
  for (int o = 1; o < 256; o <<= 1) {
    int v = (t >= o) ? tmp[t - o] : 0;
    __syncthreads();
    tmp[t] += v;
    __syncthreads();
  }
  int off = tmp[t] - s;  // exclusive
  for (int i = lo; i < hi; ++i) {
    rp[i] = off;
    cur[i] = off;
    off += deg[i];
  }
  if (t == 255) rp[n] = off;
}

__global__ __launch_bounds__(256) void k_rsqrt() {
  int i = blockIdx.x * 256 + threadIdx.x;
  if (i < N_NODES) g_dinv[i] = rsqrtf((float)(g_deg[i] + 1));
}

__global__ __launch_bounds__(256) void k_fill(const int* __restrict__ src,
                                              const int* __restrict__ dst,
                                              const int* __restrict__ c2s) {
  int i = blockIdx.x * 256 + threadIdx.x;
  if (i < N_EDGES) {
    int d = dst[i];
    int p = atomicAdd(&g_cur[d], 1);
    g_csrc[p] = src[i];
  }
  if (i < N_NODES) {
    int sp = c2s[i];
    int p = atomicAdd(&g_curs[sp], 1);
    g_cnode[p] = i;
  }
}

// ---------------- GEMM: out[nrows x 96] = act(A) @ W (*dinv) (+bias) -------
// AFF: apply per-column GN affine + ReLU while staging input to LDS.
// SCALE: multiply output row by g_dinv[row] (folds GCN symmetric norm).
template <int K, bool AFF, bool SCALE>
__global__ __launch_bounds__(256) void k_gemm96(const float* __restrict__ Aext,
                                                int a_id, int out_id,
                                                const float* __restrict__ W,
                                                const float* __restrict__ bias,
                                                int stage, int nrows) {
  __shared__ float Ws[K * HID];
  __shared__ float xs[64 * (K + 4)];
  const float* A = Aext ? Aext : pick(a_id);
  float* out = pick(out_id);
  const float* ab = g_ab + stage * 2 * HID;
  int tid = threadIdx.x;
  for (int f = tid; f < K * HID; f += 256) Ws[f] = W[f];
  int r0 = blockIdx.x * 64;
  for (int f = tid; f < 64 * K; f += 256) {
    int r = f / K, c = f - r * K;
    int row = r0 + r;
    float v = (row < nrows) ? A[row * K + c] : 0.f;
    if (AFF) v = fmaxf(v * ab[c] + ab[HID + c], 0.f);
    xs[r * (K + 4) + c] = v;
  }
  __syncthreads();
  int r = tid >> 2;
  int c0 = (tid & 3) * 24;
  float acc[24];
#pragma unroll
  for (int c = 0; c < 24; ++c) acc[c] = 0.f;
#pragma unroll 4
  for (int k = 0; k < K; ++k) {
    float xv = xs[r * (K + 4) + k];
#pragma unroll
    for (int c = 0; c < 24; ++c) acc[c] += xv * Ws[k * HID + c0 + c];
  }
  int row = r0 + r;
  if (row < nrows) {
    float sc = SCALE ? g_dinv[row] : 1.f;
#pragma unroll
    for (int c = 0; c < 24; ++c) {
      float v = acc[c] * sc;
      if (bias) v += bias[c0 + c];
      out[row * HID + c0 + c] = v;
    }
  }
}

// ---------------- GCN aggregation via CSR gather ---------------------------
// t is pre-scaled by dinv[src]; agg[d] = dinv[d]*(t[d] + sum_in t[s]) + b
__global__ __launch_bounds__(256) void k_gather(int t_id, const float* __restrict__ b,
                                                int agg_id) {
  const float* __restrict__ t = pick(t_id);
  float* __restrict__ agg = pick(agg_id);
  int g = (blockIdx.x * 256 + threadIdx.x) >> 5;
  int lane = threadIdx.x & 31;
  if (g >= N_NODES) return;
  int beg = g_rp[g], end = g_rp[g + 1];
  float a0 = t[g * HID + lane];
  float a1 = t[g * HID + 32 + lane];
  float a2 = t[g * HID + 64 + lane];
  for (int e = beg; e < end; ++e) {
    int s = g_csrc[e];
    const float* __restrict__ ts = t + s * HID;
    a0 += ts[lane];
    a1 += ts[32 + lane];
    a2 += ts[64 + lane];
  }
  float di = g_dinv[g];
  agg[g * HID + lane]      = di * a0 + b[lane];
  agg[g * HID + 32 + lane] = di * a1 + b[32 + lane];
  agg[g * HID + 64 + lane] = di * a2 + b[64 + lane];
}

// ---------------- GraphNorm stats ------------------------------------------
__global__ __launch_bounds__(256) void k_colstats(int x_id, int stage, int nrows) {
  const float* x = pick(x_id);
  float* S = g_S + stage * 2 * HID;
  int t = threadIdx.x;
  if (t >= 192) return;
  int c = (t < 96) ? t : t - 96;
  int phase = t / 96;
  int r0 = blockIdx.x * 512;
  int rend = min(r0 + 512, nrows);
  float s1 = 0.f, s2 = 0.f;
  for (int r = r0 + phase; r < rend; r += 2) {
    float v = x[r * HID + c];
    s1 += v;
    s2 += v * v;
  }
  atomicAdd(&S[c], s1);
  atomicAdd(&S[HID + c], s2);
}

// y = w*(x - a*mean)*rsqrt(var+eps) + b  ==  x*alpha + beta
__global__ void k_gnparams(int stage, const float* __restrict__ w,
                           const float* __restrict__ b, const float* __restrict__ a,
                           float invn) {
  int c = threadIdx.x;
  if (c < HID) {
    const float* S = g_S + stage * 2 * HID;
    float* ab = g_ab + stage * 2 * HID;
    float mean = S[c] * invn;
    float var = S[HID + c] * invn + mean * mean * (a[c] * a[c] - 2.f * a[c]);
    float r = rsqrtf(var + GN_EPS);
    float alpha = w[c] * r;
    ab[c] = alpha;
    ab[HID + c] = b[c] - alpha * a[c] * mean;
  }
}

// ---------------- attention scores (fused GN affine on input) --------------
__global__ __launch_bounds__(256) void k_scores(int h_id, int stage,
                                                const float* __restrict__ W1,
                                                const float* __restrict__ b1,
                                                const float* __restrict__ W2,
                                                const float* __restrict__ b2) {
  __shared__ float W1s[HID * ATTN_HID];
  __shared__ float b1s[ATTN_HID], W2s[ATTN_HID];
  __shared__ float abs_[2 * HID];
  const float* h = pick(h_id);
  const float* ab = g_ab + stage * 2 * HID;
  int tid = threadIdx.x;
  for (int f = tid; f < HID * ATTN_HID; f += 256) W1s[f] = W1[f];
  if (tid < ATTN_HID) { b1s[tid] = b1[tid]; W2s[tid] = W2[tid]; }
  if (tid < 2 * HID) abs_[tid] = ab[tid];
  __syncthreads();
  int i = blockIdx.x * 256 + tid;
  if (i >= N_NODES) return;
  float acc[ATTN_HID];
#pragma unroll
  for (int k = 0; k < ATTN_HID; ++k) acc[k] = 0.f;
  for (int j = 0; j < HID; ++j) {
    float hv = fmaxf(h[i * HID + j] * abs_[j] + abs_[HID + j], 0.f);
#pragma unroll
    for (int k = 0; k < ATTN_HID; ++k) acc[k] += hv * W1s[j * ATTN_HID + k];
  }
  float s = b2[0];
#pragma unroll
  for (int k = 0; k < ATTN_HID; ++k) s += fmaxf(acc[k] + b1s[k], 0.f) * W2s[k];
  g_scores[i] = s;
}

// ---------------- segment softmax + weighted aggregation (CSR, no atomics) -
__global__ __launch_bounds__(256) void k_spotagg(int h_id, int stage) {
  const float* __restrict__ h = pick(h_id);
  const float* ab = g_ab + stage * 2 * HID;
  int g = (blockIdx.x * 256 + threadIdx.x) >> 5;
  int lane = threadIdx.x & 31;
  if (g >= N_SPOTS) return;
  int beg = g_rps[g], end = g_rps[g + 1];
  // segment max (lane-parallel over member nodes, then 32-lane reduce)
  float m = -1e30f;
  for (int i = beg + lane; i < end; i += 32) m = fmaxf(m, g_scores[g_cnode[i]]);
#pragma unroll
  for (int o = 16; o >= 1; o >>= 1) m = fmaxf(m, __shfl_xor(m, o));
  // weighted sum (dims across lanes; exp recomputed redundantly per lane)
  float al0 = ab[lane],      be0 = ab[HID + lane];
  float al1 = ab[32 + lane], be1 = ab[HID + 32 + lane];
  float al2 = ab[64 + lane], be2 = ab[HID + 64 + lane];
  float a0 = 0.f, a1 = 0.f, a2 = 0.f, denom = 0.f;
  for (int i = beg; i < end; ++i) {
    int nd = g_cnode[i];
    float e = __expf(g_scores[nd] - m);
    denom += e;
    const float* __restrict__ hr = h + nd * HID;
    a0 += e * fmaxf(hr[lane] * al0 + be0, 0.f);
    a1 += e * fmaxf(hr[32 + lane] * al1 + be1, 0.f);
    a2 += e * fmaxf(hr[64 + lane] * al2 + be2, 0.f);
  }
  float inv = (denom > 0.f) ? 1.f / denom : 0.f;
  g_spot[g * HID + lane]      = a0 * inv;
  g_spot[g * HID + 32 + lane] = a1 * inv;
  g_spot[g * HID + 64 + lane] = a2 * inv;
}

// ---------------- final: out = relu(gn(t3)) @ mlp_W2 + b2 ------------------
__global__ __launch_bounds__(256) void k_final(int t3_id, int stage,
                                               const float* __restrict__ W2,
                                               const float* __restrict__ b2,
                                               float* __restrict__ out) {
  __shared__ float W2s[HID * OUT_DIM];
  const float* t3 = pick(t3_id);
  const float* ab = g_ab + stage * 2 * HID;
  int tid = threadIdx.x;
  for (int f = tid; f < HID * OUT_DIM; f += 256) W2s[f] = W2[f];
  __syncthreads();
  int r = blockIdx.x * 16 + (tid >> 4);
  int c = tid & 15;
  if (r >= N_SPOTS) return;
  float acc = b2[c];
  for (int j = 0; j < HID; ++j) {
    float z = fmaxf(t3[r * HID + j] * ab[j] + ab[HID + j], 0.f);
    acc += z * W2s[j * OUT_DIM + c];
  }
  out[r * OUT_DIM + c] = acc;
}

// ---------------------------------------------------------------------------
extern "C" void kernel_launch(void* const* d_in, const int* in_sizes, int n_in,
                              void* d_out, int out_size, void* d_ws, size_t ws_size,
                              hipStream_t stream) {
  const float* x       = (const float*)d_in[0];
  const int*   ei      = (const int*)d_in[1];
  const int*   src     = ei;
  const int*   dst     = ei + N_EDGES;
  const int*   c2s     = (const int*)d_in[2];
  const float* proj_W  = (const float*)d_in[4];
  const float* proj_b  = (const float*)d_in[5];
  const float* gn0_w   = (const float*)d_in[6];
  const float* gn0_b   = (const float*)d_in[7];
  const float* gn0_a   = (const float*)d_in[8];
  const float* gcn1_W  = (const float*)d_in[9];
  const float* gcn1_b  = (const float*)d_in[10];
  const float* gn1_w   = (const float*)d_in[11];
  const float* gn1_b   = (const float*)d_in[12];
  const float* gn1_a   = (const float*)d_in[13];
  const float* gcn2_W  = (const float*)d_in[14];
  const float* gcn2_b  = (const float*)d_in[15];
  const float* gn2_w   = (const float*)d_in[16];
  const float* gn2_b   = (const float*)d_in[17];
  const float* gn2_a   = (const float*)d_in[18];
  const float* attn_W1 = (const float*)d_in[19];
  const float* attn_b1 = (const float*)d_in[20];
  const float* attn_W2 = (const float*)d_in[21];
  const float* attn_b2 = (const float*)d_in[22];
  const float* mlp_W1  = (const float*)d_in[23];
  const float* mlp_b1  = (const float*)d_in[24];
  const float* mlp_gn_w = (const float*)d_in[25];
  const float* mlp_gn_b = (const float*)d_in[26];
  const float* mlp_gn_a = (const float*)d_in[27];
  const float* mlp_W2  = (const float*)d_in[28];
  const float* mlp_b2  = (const float*)d_in[29];
  float* out = (float*)d_out;

  const float invN = 1.f / (float)N_NODES;
  const float invS = 1.f / (float)N_SPOTS;
  const int GB_N = (N_NODES + 63) / 64;
  const int GB_S = (N_SPOTS + 63) / 64;
  const int CS_N = (N_NODES + 511) / 512;
  const int CS_S = (N_SPOTS + 511) / 512;
  const int EB   = (N_EDGES + 255) / 256;
  const int GTH  = (N_NODES * 32 + 255) / 256;   // gather blocks
  const int SPB  = (N_SPOTS * 32 + 255) / 256;   // spotagg blocks

  // ---- CSR build (edges by dst; nodes by spot) ----
  k_init<<<(N_NODES + 255) / 256, 256, 0, stream>>>();
  k_hist<<<EB, 256, 0, stream>>>(dst, c2s);
  k_scan<<<2, 256, 0, stream>>>();
  k_rsqrt<<<(N_NODES + 255) / 256, 256, 0, stream>>>();
  k_fill<<<EB, 256, 0, stream>>>(src, dst, c2s);

  // ---- stage 0: proj ----
  k_gemm96<IN_DIM, false, false><<<GB_N, 256, 0, stream>>>(x, -1, 0, proj_W, proj_b, 0, N_NODES);
  k_colstats<<<CS_N, 256, 0, stream>>>(0, 0, N_NODES);
  k_gnparams<<<1, 128, 0, stream>>>(0, gn0_w, gn0_b, gn0_a, invN);

  // ---- GCN layer 1: t1' = (relu(gn0(t0)) @ W1) * dinv -> bufB; gather -> bufA
  k_gemm96<HID, true, true><<<GB_N, 256, 0, stream>>>(nullptr, 0, 1, gcn1_W, nullptr, 0, N_NODES);
  k_gather<<<GTH, 256, 0, stream>>>(1, gcn1_b, 0);
  k_colstats<<<CS_N, 256, 0, stream>>>(0, 1, N_NODES);
  k_gnparams<<<1, 128, 0, stream>>>(1, gn1_w, gn1_b, gn1_a, invN);

  // ---- GCN layer 2: t2' -> bufC; gather -> bufB
  k_gemm96<HID, true, true><<<GB_N, 256, 0, stream>>>(nullptr, 0, 2, gcn2_W, nullptr, 1, N_NODES);
  k_gather<<<GTH, 256, 0, stream>>>(2, gcn2_b, 1);
  k_colstats<<<CS_N, 256, 0, stream>>>(1, 2, N_NODES);
  k_gnparams<<<1, 128, 0, stream>>>(2, gn2_w, gn2_b, gn2_a, invN);

  // ---- attention + segment softmax + spot aggregation (affine fused) ----
  k_scores<<<(N_NODES + 255) / 256, 256, 0, stream>>>(1, 2, attn_W1, attn_b1, attn_W2, attn_b2);
  k_spotagg<<<SPB, 256, 0, stream>>>(1, 2);

  // ---- MLP head ----
  k_gemm96<HID, false, false><<<GB_S, 256, 0, stream>>>(nullptr, 3, 2, mlp_W1, mlp_b1, 0, N_SPOTS);
  k_colstats<<<CS_S, 256, 0, stream>>>(2, 3, N_SPOTS);
  k_gnparams<<<1, 128, 0, stream>>>(3, mlp_gn_w, mlp_gn_b, mlp_gn_a, invS);
  k_final<<<(N_SPOTS + 15) / 16, 256, 0, stream>>>(2, 3, mlp_W2, mlp_b2, out);
}

// Round 3
// 567.177 us; speedup vs baseline: 2.4282x; 1.5606x over previous
//
#include <hip/hip_runtime.h>

#define N_NODES 50000
#define N_EDGES 800000
#define IN_DIM 128
#define HID 96
#define ATTN_HID 32
#define OUT_DIM 16
#define N_SPOTS 5000
#define GN_EPS 1e-5f

#define SCAN_NB ((N_NODES + 255) / 256)   // 196
#define SCAN_SB ((N_SPOTS + 255) / 256)   // 20

// ---------------- persistent device scratch (re-initialized every call) ----
__device__ float    g_bufA[N_NODES * HID];
__device__ float    g_bufB[N_NODES * HID];
__device__ float    g_bufC[N_NODES * HID];
__device__ float    g_spot[N_SPOTS * HID];
__device__ float    g_dinv[N_NODES];      // rsqrt(deg+1)
__device__ float    g_scores[N_NODES];
__device__ int      g_deg[N_NODES];       // in-degree histogram (edges)
__device__ int      g_degs[N_SPOTS];      // spot histogram (nodes)
__device__ int      g_rp[N_NODES + 1];    // CSR row ptr (by dst)
__device__ int      g_cur[N_NODES];       // fill cursors
__device__ int      g_rps[N_SPOTS + 1];   // spot CSR row ptr
__device__ int      g_curs[N_SPOTS];
__device__ int      g_csrc[N_EDGES];      // CSR src indices
__device__ int      g_cnode[N_NODES];     // spot CSR node indices
__device__ int      g_partN[SCAN_NB];     // scan partials (nodes)
__device__ int      g_partS[SCAN_SB];     // scan partials (spots)
__device__ float    g_S[4 * 2 * HID];     // 4 GN stages x (colsum, colsumsq)
__device__ float    g_ab[4 * 2 * HID];    // 4 GN stages x (alpha, beta)

__device__ __forceinline__ float* pick(int id) {
  switch (id) {
    case 0:  return g_bufA;
    case 1:  return g_bufB;
    case 2:  return g_bufC;
    default: return g_spot;
  }
}

// ---------------- init: zero histograms + GN sums --------------------------
__global__ __launch_bounds__(256) void k_init() {
  int i = blockIdx.x * 256 + threadIdx.x;
  if (i < N_NODES) g_deg[i] = 0;
  if (i < N_SPOTS) g_degs[i] = 0;
  if (i < 4 * 2 * HID) g_S[i] = 0.f;
}

// histograms: edge->dst degree, node->spot counts
__global__ __launch_bounds__(256) void k_hist(const int* __restrict__ dst,
                                              const int* __restrict__ c2s) {
  int i = blockIdx.x * 256 + threadIdx.x;
  if (i < N_EDGES) atomicAdd(&g_deg[dst[i]], 1);
  if (i < N_NODES) atomicAdd(&g_degs[c2s[i]], 1);
}

// ---------------- hierarchical exclusive scan (nodes + spots) --------------
// phase 1: per-block (256-elem) totals
__global__ __launch_bounds__(256) void k_scan1() {
  bool isS = blockIdx.x >= SCAN_NB;
  int b = isS ? blockIdx.x - SCAN_NB : blockIdx.x;
  const int n = isS ? N_SPOTS : N_NODES;
  const int* deg = isS ? g_degs : g_deg;
  int i = b * 256 + threadIdx.x;
  int v = (i < n) ? deg[i] : 0;
#pragma unroll
  for (int o = 32; o >= 1; o >>= 1) v += __shfl_xor(v, o);
  __shared__ int red[4];
  if ((threadIdx.x & 63) == 0) red[threadIdx.x >> 6] = v;
  __syncthreads();
  if (threadIdx.x == 0)
    (isS ? g_partS : g_partN)[b] = red[0] + red[1] + red[2] + red[3];
}

// phase 2: scan the partials (block 0 = nodes, block 1 = spots)
__global__ __launch_bounds__(256) void k_scan2() {
  bool isS = blockIdx.x == 1;
  int cnt = isS ? SCAN_SB : SCAN_NB;
  int* part = isS ? g_partS : g_partN;
  __shared__ int tmp[256];
  int t = threadIdx.x;
  int v = (t < cnt) ? part[t] : 0;
  tmp[t] = v;
  __syncthreads();
  for (int o = 1; o < 256; o <<= 1) {
    int u = (t >= o) ? tmp[t - o] : 0;
    __syncthreads();
    tmp[t] += u;
    __syncthreads();
  }
  if (t < cnt) part[t] = tmp[t] - v;  // exclusive
}

// phase 3: block-local scan + global offset -> rp/cur; fuse dinv = rsqrt(deg+1)
__global__ __launch_bounds__(256) void k_scan3() {
  bool isS = blockIdx.x >= SCAN_NB;
  int b = isS ? blockIdx.x - SCAN_NB : blockIdx.x;
  const int n = isS ? N_SPOTS : N_NODES;
  const int* deg = isS ? g_degs : g_deg;
  int* rp  = isS ? g_rps  : g_rp;
  int* cur = isS ? g_curs : g_cur;
  const int* part = isS ? g_partS : g_partN;
  __shared__ int tmp[256];
  int t = threadIdx.x;
  int i = b * 256 + t;
  int v = (i < n) ? deg[i] : 0;
  tmp[t] = v;
  __syncthreads();
  for (int o = 1; o < 256; o <<= 1) {
    int u = (t >= o) ? tmp[t - o] : 0;
    __syncthreads();
    tmp[t] += u;
    __syncthreads();
  }
  if (i < n) {
    int off = part[b] + tmp[t] - v;  // exclusive position
    rp[i] = off;
    cur[i] = off;
    if (i == n - 1) rp[n] = off + v;
    if (!isS) g_dinv[i] = rsqrtf((float)(v + 1));
  }
}

__global__ __launch_bounds__(256) void k_fill(const int* __restrict__ src,
                                              const int* __restrict__ dst,
                                              const int* __restrict__ c2s) {
  int i = blockIdx.x * 256 + threadIdx.x;
  if (i < N_EDGES) {
    int d = dst[i];
    int p = atomicAdd(&g_cur[d], 1);
    g_csrc[p] = src[i];
  }
  if (i < N_NODES) {
    int sp = c2s[i];
    int p = atomicAdd(&g_curs[sp], 1);
    g_cnode[p] = i;
  }
}

// ---------------- GEMM: out[nrows x 96] = act(A) @ W (*dinv) (+bias) -------
// 128-row tile, K chunked by 32; each thread: 4 rows x 12 cols.
// AFF: per-column GN affine + ReLU while staging input to LDS.
// SCALE: multiply output row by g_dinv[row] (folds GCN symmetric norm).
template <int K, bool AFF, bool SCALE>
__global__ __launch_bounds__(256) void k_gemm96(const float* __restrict__ Aext,
                                                int a_id, int out_id,
                                                const float* __restrict__ W,
                                                const float* __restrict__ bias,
                                                int stage, int nrows) {
  constexpr int KC = 32;
  constexpr int ROWS = 128;
  __shared__ __align__(16) float Ws[KC][HID];       // 12 KB
  __shared__ float xs[ROWS][KC + 1];                // 16.5 KB
  __shared__ float abs_[2 * HID];
  const float* A = Aext ? Aext : pick(a_id);
  float* out = pick(out_id);
  int tid = threadIdx.x;
  if (AFF && tid < 2 * HID) abs_[tid] = g_ab[stage * 2 * HID + tid];
  int r0 = blockIdx.x * ROWS;
  int rg = tid >> 3;            // 0..31
  int cg = (tid & 7) * 12;      // 0..84
  float acc[4][12];
#pragma unroll
  for (int i = 0; i < 4; ++i)
#pragma unroll
    for (int c = 0; c < 12; ++c) acc[i][c] = 0.f;

  for (int k0 = 0; k0 < K; k0 += KC) {
    __syncthreads();  // previous chunk fully consumed (also covers abs_ staging)
    // stage W chunk: KC*96 floats = 768 float4
    for (int f = tid; f < KC * HID / 4; f += 256) {
      reinterpret_cast<float4*>(&Ws[0][0])[f] =
          reinterpret_cast<const float4*>(W + (size_t)k0 * HID)[f];
    }
    // stage A chunk: ROWS x KC = 1024 float4
    for (int f = tid; f < ROWS * KC / 4; f += 256) {
      int r = f >> 3;
      int kk = (f & 7) << 2;
      int row = r0 + r;
      float4 v = make_float4(0.f, 0.f, 0.f, 0.f);
      if (row < nrows)
        v = *reinterpret_cast<const float4*>(A + (size_t)row * K + k0 + kk);
      if (AFF) {
        int c = k0 + kk;
        v.x = fmaxf(v.x * abs_[c]     + abs_[HID + c],     0.f);
        v.y = fmaxf(v.y * abs_[c + 1] + abs_[HID + c + 1], 0.f);
        v.z = fmaxf(v.z * abs_[c + 2] + abs_[HID + c + 2], 0.f);
        v.w = fmaxf(v.w * abs_[c + 3] + abs_[HID + c + 3], 0.f);
      }
      xs[r][kk] = v.x; xs[r][kk + 1] = v.y; xs[r][kk + 2] = v.z; xs[r][kk + 3] = v.w;
    }
    __syncthreads();
#pragma unroll
    for (int k = 0; k < KC; ++k) {
      float x0 = xs[rg][k];
      float x1 = xs[rg + 32][k];
      float x2 = xs[rg + 64][k];
      float x3 = xs[rg + 96][k];
#pragma unroll
      for (int c = 0; c < 12; ++c) {
        float wv = Ws[k][cg + c];
        acc[0][c] += x0 * wv;
        acc[1][c] += x1 * wv;
        acc[2][c] += x2 * wv;
        acc[3][c] += x3 * wv;
      }
    }
  }
#pragma unroll
  for (int i = 0; i < 4; ++i) {
    int row = r0 + rg + 32 * i;
    if (row < nrows) {
      float sc = SCALE ? g_dinv[row] : 1.f;
#pragma unroll
      for (int c = 0; c < 12; ++c) {
        float v = acc[i][c] * sc;
        if (bias) v += bias[cg + c];
        out[(size_t)row * HID + cg + c] = v;
      }
    }
  }
}

// ---------------- GCN aggregation via CSR gather ---------------------------
// t is pre-scaled by dinv[src]; agg[d] = dinv[d]*(t[d] + sum_in t[s]) + b
__global__ __launch_bounds__(256) void k_gather(int t_id, const float* __restrict__ b,
                                                int agg_id) {
  const float* __restrict__ t = pick(t_id);
  float* __restrict__ agg = pick(agg_id);
  int g = (blockIdx.x * 256 + threadIdx.x) >> 5;
  int lane = threadIdx.x & 31;
  if (g >= N_NODES) return;
  int beg = g_rp[g], end = g_rp[g + 1];
  float a0 = t[g * HID + lane];
  float a1 = t[g * HID + 32 + lane];
  float a2 = t[g * HID + 64 + lane];
  for (int e = beg; e < end; ++e) {
    int s = g_csrc[e];
    const float* __restrict__ ts = t + (size_t)s * HID;
    a0 += ts[lane];
    a1 += ts[32 + lane];
    a2 += ts[64 + lane];
  }
  float di = g_dinv[g];
  agg[g * HID + lane]      = di * a0 + b[lane];
  agg[g * HID + 32 + lane] = di * a1 + b[32 + lane];
  agg[g * HID + 64 + lane] = di * a2 + b[64 + lane];
}

// ---------------- GraphNorm stats ------------------------------------------
__global__ __launch_bounds__(256) void k_colstats(int x_id, int stage, int nrows) {
  const float* x = pick(x_id);
  float* S = g_S + stage * 2 * HID;
  int t = threadIdx.x;
  if (t >= 192) return;
  int c = (t < 96) ? t : t - 96;
  int phase = t / 96;
  int r0 = blockIdx.x * 128;
  int rend = min(r0 + 128, nrows);
  float s1 = 0.f, s2 = 0.f;
  for (int r = r0 + phase; r < rend; r += 2) {
    float v = x[(size_t)r * HID + c];
    s1 += v;
    s2 += v * v;
  }
  atomicAdd(&S[c], s1);
  atomicAdd(&S[HID + c], s2);
}

// y = w*(x - a*mean)*rsqrt(var+eps) + b  ==  x*alpha + beta
__global__ void k_gnparams(int stage, const float* __restrict__ w,
                           const float* __restrict__ b, const float* __restrict__ a,
                           float invn) {
  int c = threadIdx.x;
  if (c < HID) {
    const float* S = g_S + stage * 2 * HID;
    float* ab = g_ab + stage * 2 * HID;
    float mean = S[c] * invn;
    float var = S[HID + c] * invn + mean * mean * (a[c] * a[c] - 2.f * a[c]);
    float r = rsqrtf(var + GN_EPS);
    float alpha = w[c] * r;
    ab[c] = alpha;
    ab[HID + c] = b[c] - alpha * a[c] * mean;
  }
}

// ---------------- attention scores (fused GN affine on input) --------------
__global__ __launch_bounds__(256) void k_scores(int h_id, int stage,
                                                const float* __restrict__ W1,
                                                const float* __restrict__ b1,
                                                const float* __restrict__ W2,
                                                const float* __restrict__ b2) {
  __shared__ float W1s[HID * ATTN_HID];
  __shared__ float b1s[ATTN_HID], W2s[ATTN_HID];
  __shared__ float abs_[2 * HID];
  const float* h = pick(h_id);
  const float* ab = g_ab + stage * 2 * HID;
  int tid = threadIdx.x;
  for (int f = tid; f < HID * ATTN_HID; f += 256) W1s[f] = W1[f];
  if (tid < ATTN_HID) { b1s[tid] = b1[tid]; W2s[tid] = W2[tid]; }
  if (tid < 2 * HID) abs_[tid] = ab[tid];
  __syncthreads();
  int i = blockIdx.x * 256 + tid;
  if (i >= N_NODES) return;
  float acc[ATTN_HID];
#pragma unroll
  for (int k = 0; k < ATTN_HID; ++k) acc[k] = 0.f;
  for (int j = 0; j < HID; ++j) {
    float hv = fmaxf(h[(size_t)i * HID + j] * abs_[j] + abs_[HID + j], 0.f);
#pragma unroll
    for (int k = 0; k < ATTN_HID; ++k) acc[k] += hv * W1s[j * ATTN_HID + k];
  }
  float s = b2[0];
#pragma unroll
  for (int k = 0; k < ATTN_HID; ++k) s += fmaxf(acc[k] + b1s[k], 0.f) * W2s[k];
  g_scores[i] = s;
}

// ---------------- segment softmax + weighted aggregation (CSR, no atomics) -
__global__ __launch_bounds__(256) void k_spotagg(int h_id, int stage) {
  const float* __restrict__ h = pick(h_id);
  const float* ab = g_ab + stage * 2 * HID;
  int g = (blockIdx.x * 256 + threadIdx.x) >> 5;
  int lane = threadIdx.x & 31;
  if (g >= N_SPOTS) return;
  int beg = g_rps[g], end = g_rps[g + 1];
  float m = -1e30f;
  for (int i = beg + lane; i < end; i += 32) m = fmaxf(m, g_scores[g_cnode[i]]);
#pragma unroll
  for (int o = 16; o >= 1; o >>= 1) m = fmaxf(m, __shfl_xor(m, o));
  float al0 = ab[lane],      be0 = ab[HID + lane];
  float al1 = ab[32 + lane], be1 = ab[HID + 32 + lane];
  float al2 = ab[64 + lane], be2 = ab[HID + 64 + lane];
  float a0 = 0.f, a1 = 0.f, a2 = 0.f, denom = 0.f;
  for (int i = beg; i < end; ++i) {
    int nd = g_cnode[i];
    float e = __expf(g_scores[nd] - m);
    denom += e;
    const float* __restrict__ hr = h + (size_t)nd * HID;
    a0 += e * fmaxf(hr[lane] * al0 + be0, 0.f);
    a1 += e * fmaxf(hr[32 + lane] * al1 + be1, 0.f);
    a2 += e * fmaxf(hr[64 + lane] * al2 + be2, 0.f);
  }
  float inv = (denom > 0.f) ? 1.f / denom : 0.f;
  g_spot[g * HID + lane]      = a0 * inv;
  g_spot[g * HID + 32 + lane] = a1 * inv;
  g_spot[g * HID + 64 + lane] = a2 * inv;
}

// ---------------- final: out = relu(gn(t3)) @ mlp_W2 + b2 ------------------
__global__ __launch_bounds__(256) void k_final(int t3_id, int stage,
                                               const float* __restrict__ W2,
                                               const float* __restrict__ b2,
                                               float* __restrict__ out) {
  __shared__ float W2s[HID * OUT_DIM];
  const float* t3 = pick(t3_id);
  const float* ab = g_ab + stage * 2 * HID;
  int tid = threadIdx.x;
  for (int f = tid; f < HID * OUT_DIM; f += 256) W2s[f] = W2[f];
  __syncthreads();
  int r = blockIdx.x * 16 + (tid >> 4);
  int c = tid & 15;
  if (r >= N_SPOTS) return;
  float acc = b2[c];
  for (int j = 0; j < HID; ++j) {
    float z = fmaxf(t3[(size_t)r * HID + j] * ab[j] + ab[HID + j], 0.f);
    acc += z * W2s[j * OUT_DIM + c];
  }
  out[r * OUT_DIM + c] = acc;
}

// ---------------------------------------------------------------------------
extern "C" void kernel_launch(void* const* d_in, const int* in_sizes, int n_in,
                              void* d_out, int out_size, void* d_ws, size_t ws_size,
                              hipStream_t stream) {
  const float* x       = (const float*)d_in[0];
  const int*   ei      = (const int*)d_in[1];
  const int*   src     = ei;
  const int*   dst     = ei + N_EDGES;
  const int*   c2s     = (const int*)d_in[2];
  const float* proj_W  = (const float*)d_in[4];
  const float* proj_b  = (const float*)d_in[5];
  const float* gn0_w   = (const float*)d_in[6];
  const float* gn0_b   = (const float*)d_in[7];
  const float* gn0_a   = (const float*)d_in[8];
  const float* gcn1_W  = (const float*)d_in[9];
  const float* gcn1_b  = (const float*)d_in[10];
  const float* gn1_w   = (const float*)d_in[11];
  const float* gn1_b   = (const float*)d_in[12];
  const float* gn1_a   = (const float*)d_in[13];
  const float* gcn2_W  = (const float*)d_in[14];
  const float* gcn2_b  = (const float*)d_in[15];
  const float* gn2_w   = (const float*)d_in[16];
  const float* gn2_b   = (const float*)d_in[17];
  const float* gn2_a   = (const float*)d_in[18];
  const float* attn_W1 = (const float*)d_in[19];
  const float* attn_b1 = (const float*)d_in[20];
  const float* attn_W2 = (const float*)d_in[21];
  const float* attn_b2 = (const float*)d_in[22];
  const float* mlp_W1  = (const float*)d_in[23];
  const float* mlp_b1  = (const float*)d_in[24];
  const float* mlp_gn_w = (const float*)d_in[25];
  const float* mlp_gn_b = (const float*)d_in[26];
  const float* mlp_gn_a = (const float*)d_in[27];
  const float* mlp_W2  = (const float*)d_in[28];
  const float* mlp_b2  = (const float*)d_in[29];
  float* out = (float*)d_out;

  const float invN = 1.f / (float)N_NODES;
  const float invS = 1.f / (float)N_SPOTS;
  const int GB_N = (N_NODES + 127) / 128;   // 391
  const int GB_S = (N_SPOTS + 127) / 128;   // 40
  const int CS_N = (N_NODES + 127) / 128;
  const int CS_S = (N_SPOTS + 127) / 128;
  const int EB   = (N_EDGES + 255) / 256;
  const int GTH  = (N_NODES * 32 + 255) / 256;
  const int SPB  = (N_SPOTS * 32 + 255) / 256;
  const int SCB  = SCAN_NB + SCAN_SB;       // 216

  // ---- CSR build (edges by dst; nodes by spot) ----
  k_init<<<(N_NODES + 255) / 256, 256, 0, stream>>>();
  k_hist<<<EB, 256, 0, stream>>>(dst, c2s);
  k_scan1<<<SCB, 256, 0, stream>>>();
  k_scan2<<<2, 256, 0, stream>>>();
  k_scan3<<<SCB, 256, 0, stream>>>();
  k_fill<<<EB, 256, 0, stream>>>(src, dst, c2s);

  // ---- stage 0: proj ----
  k_gemm96<IN_DIM, false, false><<<GB_N, 256, 0, stream>>>(x, -1, 0, proj_W, proj_b, 0, N_NODES);
  k_colstats<<<CS_N, 256, 0, stream>>>(0, 0, N_NODES);
  k_gnparams<<<1, 128, 0, stream>>>(0, gn0_w, gn0_b, gn0_a, invN);

  // ---- GCN layer 1: t1' = (relu(gn0(t0)) @ W1) * dinv -> bufB; gather -> bufA
  k_gemm96<HID, true, true><<<GB_N, 256, 0, stream>>>(nullptr, 0, 1, gcn1_W, nullptr, 0, N_NODES);
  k_gather<<<GTH, 256, 0, stream>>>(1, gcn1_b, 0);
  k_colstats<<<CS_N, 256, 0, stream>>>(0, 1, N_NODES);
  k_gnparams<<<1, 128, 0, stream>>>(1, gn1_w, gn1_b, gn1_a, invN);

  // ---- GCN layer 2: t2' -> bufC; gather -> bufB
  k_gemm96<HID, true, true><<<GB_N, 256, 0, stream>>>(nullptr, 0, 2, gcn2_W, nullptr, 1, N_NODES);
  k_gather<<<GTH, 256, 0, stream>>>(2, gcn2_b, 1);
  k_colstats<<<CS_N, 256, 0, stream>>>(1, 2, N_NODES);
  k_gnparams<<<1, 128, 0, stream>>>(2, gn2_w, gn2_b, gn2_a, invN);

  // ---- attention + segment softmax + spot aggregation (affine fused) ----
  k_scores<<<(N_NODES + 255) / 256, 256, 0, stream>>>(1, 2, attn_W1, attn_b1, attn_W2, attn_b2);
  k_spotagg<<<SPB, 256, 0, stream>>>(1, 2);

  // ---- MLP head ----
  k_gemm96<HID, false, false><<<GB_S, 256, 0, stream>>>(nullptr, 3, 2, mlp_W1, mlp_b1, 0, N_SPOTS);
  k_colstats<<<CS_S, 256, 0, stream>>>(2, 3, N_SPOTS);
  k_gnparams<<<1, 128, 0, stream>>>(3, mlp_gn_w, mlp_gn_b, mlp_gn_a, invS);
  k_final<<<(N_SPOTS + 15) / 16, 256, 0, stream>>>(2, 3, mlp_W2, mlp_b2, out);
}